// Round 10
// baseline (53.532 us; speedup 1.0000x reference)
//
#include <hip/hip_runtime.h>
#include <hip/hip_fp16.h>

#define N_ROWS 1024
#define DIM 256
#define HID 512

typedef _Float16 half_t;
typedef __attribute__((ext_vector_type(8))) _Float16 half8v;
typedef __attribute__((ext_vector_type(16))) float f32x16;

struct Params {
    const float* a;
    const float* b;
    const float* w[6];      // w0m,w0l,w1m,w1l,w2m,w2l (fp32, K x N)
    const float* bias[6];
    unsigned* flags;        // [32], single producer each, target 1
    float* acc;
    unsigned* done;         // target 32
    float* ebsum;           // [256]
    float* eb2sum;          // [256]
    float* g_mu;            // [1024][256] f32 handoff
    half_t* wt[6];          // transposed f16 weights (N x K)
    float* out;
};

// ---------------- prep: weight transpose+convert, colstats (r3/r5 validated) ----
__global__ __launch_bounds__(256) void prep_kernel(Params p) {
    __shared__ float T[32][33];
    const int y = blockIdx.y, bx = blockIdx.x, tid = threadIdx.x;

    if (y == 6) {           // colstats: 64 blocks x 16 rows
        if (bx >= 64) return;
        const int d = tid, r0 = bx * 16;
        float s = 0.f, s2 = 0.f;
        #pragma unroll
        for (int r = 0; r < 16; ++r) {
            float v = p.b[(r0 + r) * DIM + d];
            s += v; s2 = fmaf(v, v, s2);
        }
        atomicAdd(&p.ebsum[d], s);
        atomicAdd(&p.eb2sum[d], s2);
        return;
    }
    const float* src = p.w[y];
    half_t* dst = p.wt[y];
    const int K = (y < 2) ? DIM : HID;
    const int N = (y < 4) ? HID : DIM;
    const int ltpr = (N == HID) ? 4 : 3;
    const int ntiles = (K >> 5) << ltpr;
    if (bx >= ntiles) return;
    const int tk = bx >> ltpr, tn = bx & ((1 << ltpr) - 1);
    const int r = tid >> 3, c4 = (tid & 7) * 4;
    float4 v = *(const float4*)&src[(tk * 32 + r) * N + tn * 32 + c4];
    T[r][c4 + 0] = v.x; T[r][c4 + 1] = v.y; T[r][c4 + 2] = v.z; T[r][c4 + 3] = v.w;
    __syncthreads();
    half_t h0 = (half_t)T[c4 + 0][r];
    half_t h1 = (half_t)T[c4 + 1][r];
    half_t h2 = (half_t)T[c4 + 2][r];
    half_t h3 = (half_t)T[c4 + 3][r];
    half_t* dp = &dst[(tn * 32 + r) * K + tk * 32 + c4];
    dp[0] = h0; dp[1] = h1; dp[2] = h2; dp[3] = h3;
}

// ---------------- one layer: A in LDS (chunk-swizzled), W from global regs ----
// Xin: LDS [NC][32][40] f16. Wt: global N x K f16. 8 waves, NT col-tiles each.
// MODE 0: relu -> Xout LDS (chunk layout). MODE 1: f32 -> gmu global (agent).
// MODE 2: f32 -> rawL LDS [32][256].
template <int NC, int NT, int MODE>
__device__ __forceinline__ void gemm_layer(const half_t* __restrict__ Xin,
                                           const half_t* __restrict__ Wt,
                                           const float* __restrict__ bias,
                                           half_t* __restrict__ Xout,
                                           float* __restrict__ rawL,
                                           float* __restrict__ gmu,
                                           const int R0) {
    constexpr int K = NC * 32;
    const int tid = threadIdx.x;
    const int w = tid >> 6, lane = tid & 63;
    const int lr = lane & 31, hi = lane >> 5;
    const int sa = (lr >> 3) & 3;
    const int aoff0 = lr * 40 + ((hi ^ sa) * 8);
    const int aoff1 = lr * 40 + (((hi + 2) ^ sa) * 8);

    #pragma unroll
    for (int ct = 0; ct < NT; ++ct) {
        const int col0 = (w * NT + ct) * 32;
        const half_t* Wp = Wt + (col0 + lr) * K + hi * 8;

        f32x16 acc;
        #pragma unroll
        for (int i = 0; i < 16; ++i) acc[i] = 0.f;

        half8v wbuf[4][2], abuf[2][2];
        #define ISSUE_W(c)                                              \
            do {                                                        \
                wbuf[(c) & 3][0] = *(const half8v*)(Wp + (c) * 32);     \
                wbuf[(c) & 3][1] = *(const half8v*)(Wp + (c) * 32 + 16);\
            } while (0)
        #define ISSUE_A(c)                                              \
            do {                                                        \
                abuf[(c) & 1][0] = *(const half8v*)&Xin[(c) * 1280 + aoff0]; \
                abuf[(c) & 1][1] = *(const half8v*)&Xin[(c) * 1280 + aoff1]; \
            } while (0)

        ISSUE_W(0); ISSUE_W(1); ISSUE_W(2); ISSUE_W(3);
        ISSUE_A(0); ISSUE_A(1);

        #pragma unroll
        for (int c = 0; c < NC; ++c) {
            half8v av0 = abuf[c & 1][0], av1 = abuf[c & 1][1];
            half8v bv0 = wbuf[c & 3][0], bv1 = wbuf[c & 3][1];
            if (c + 2 < NC) ISSUE_A(c + 2);
            if (c + 4 < NC) ISSUE_W(c + 4);
            acc = __builtin_amdgcn_mfma_f32_32x32x16_f16(av0, bv0, acc, 0, 0, 0);
            acc = __builtin_amdgcn_mfma_f32_32x32x16_f16(av1, bv1, acc, 0, 0, 0);
        }
        #undef ISSUE_W
        #undef ISSUE_A

        // epilogue: C/D layout col = lane&31, row = (reg&3)+8*(reg>>2)+4*(lane>>5)
        const int col = col0 + lr;
        const float bv = bias[col];
        #pragma unroll
        for (int r = 0; r < 16; ++r) {
            const int row = (r & 3) + 8 * (r >> 2) + 4 * hi;
            float v = acc[r] + bv;
            if (MODE == 0) {
                v = fmaxf(v, 0.f);
                const int kbp = (lr >> 3) ^ ((row >> 3) & 3);
                Xout[(col0 >> 5) * 1280 + row * 40 + kbp * 8 + (lr & 7)] = (half_t)v;
            } else if (MODE == 1) {
                __hip_atomic_store(&gmu[(R0 + row) * DIM + col], v,
                                   __ATOMIC_RELAXED, __HIP_MEMORY_SCOPE_AGENT);
            } else {
                rawL[row * 256 + col] = v;
            }
        }
    }
}

// ---------------- main: 64 blocks, whole net per block, 1 sync hop total ----
__global__ void __launch_bounds__(512) main_kernel(Params p) {
    __shared__ alignas(16) char smem[81984];
    half_t* XA = (half_t*)smem;                 // [16][32][40]
    half_t* XB = (half_t*)(smem + 40960);       // [16][32][40]
    float* rawL = (float*)(smem + 40960);       // [32][256] f32 (XB region, L2 phase)
    float* bsum = (float*)(smem + 81920);

    const int bid = blockIdx.x, tid = threadIdx.x;
    const int net = bid & 1, g = bid >> 1, R0 = g * 32;

    // ---- stage a rows -> XA chunks (fp32 -> f16, swizzled) ----
    {
        const int r = tid >> 4, q = tid & 15;
        const float* src = &p.a[(R0 + r) * DIM + q * 16];
        float4 v0 = *(const float4*)(src);
        float4 v1 = *(const float4*)(src + 4);
        float4 v2 = *(const float4*)(src + 8);
        float4 v3 = *(const float4*)(src + 12);
        half8v h0, h1;
        h0[0] = (half_t)v0.x; h0[1] = (half_t)v0.y; h0[2] = (half_t)v0.z; h0[3] = (half_t)v0.w;
        h0[4] = (half_t)v1.x; h0[5] = (half_t)v1.y; h0[6] = (half_t)v1.z; h0[7] = (half_t)v1.w;
        h1[0] = (half_t)v2.x; h1[1] = (half_t)v2.y; h1[2] = (half_t)v2.z; h1[3] = (half_t)v2.w;
        h1[4] = (half_t)v3.x; h1[5] = (half_t)v3.y; h1[6] = (half_t)v3.z; h1[7] = (half_t)v3.w;
        const int c = q >> 1, kb0 = (q & 1) * 2, s = (r >> 3) & 3;
        *(half8v*)&XA[c * 1280 + r * 40 + ((kb0 ^ s) * 8)] = h0;
        *(half8v*)&XA[c * 1280 + r * 40 + (((kb0 + 1) ^ s) * 8)] = h1;
    }
    __syncthreads();

    // ---- L0: XA(a) @ wt[net] -> XB (h1, relu), 512 cols ----
    gemm_layer<8, 2, 0>(XA, p.wt[net], p.bias[net], XB, nullptr, nullptr, R0);
    __syncthreads();
    // ---- L1: XB(h1) @ wt[2+net] -> XA (h2, relu), 512 cols ----
    gemm_layer<16, 2, 0>(XB, p.wt[2 + net], p.bias[2 + net], XA, nullptr, nullptr, R0);
    __syncthreads();

    if (net == 0) {
        // ---- L2 mu: XA(h2) @ wt[4] -> g_mu (f32, agent stores), 256 cols ----
        gemm_layer<16, 1, 1>(XA, p.wt[4], p.bias[4], nullptr, nullptr, p.g_mu, R0);
        asm volatile("s_waitcnt vmcnt(0)" ::: "memory");
        __syncthreads();
        if (tid == 0)
            __hip_atomic_store(&p.flags[g], 1u, __ATOMIC_RELAXED, __HIP_MEMORY_SCOPE_AGENT);
        return;
    }

    // ---- L2 lv: XA(h2) @ wt[5] -> rawL (LDS f32), 256 cols ----
    gemm_layer<16, 1, 2>(XA, p.wt[5], p.bias[5], nullptr, rawL, nullptr, R0);
    if (tid == 0) *bsum = 0.f;
    // wait for mu partner (single producer)
    if (tid == 0) {
        while (__hip_atomic_load(&p.flags[g], __ATOMIC_RELAXED, __HIP_MEMORY_SCOPE_AGENT) == 0u)
            __builtin_amdgcn_s_sleep(1);
    }
    __syncthreads();
    asm volatile("" ::: "memory");

    // ---- loss for rows R0..R0+31 (8 waves x 4 rows) ----
    const int wave = tid >> 6, lane = tid & 63;
    const float invN = 1.0f / (float)N_ROWS;
    float ebv[4], eb2v[4];
    #pragma unroll
    for (int t = 0; t < 4; ++t) {
        const int d = lane + t * 64;
        ebv[t]  = p.ebsum[d] * invN;
        eb2v[t] = p.eb2sum[d] * invN;
    }
    float wacc = 0.f;
    #pragma unroll
    for (int rr = 0; rr < 4; ++rr) {
        const int i = wave * 4 + rr;
        float m4[4], l4[4], ss = 0.f;
        #pragma unroll
        for (int t = 0; t < 4; ++t) {
            const int d = lane + t * 64;
            m4[t] = p.g_mu[(R0 + i) * DIM + d];
            l4[t] = rawL[i * 256 + d];
            ss = fmaf(m4[t], m4[t], ss);
        }
        #pragma unroll
        for (int o = 32; o > 0; o >>= 1) ss += __shfl_xor(ss, o, 64);
        const float inv_norm = 1.f / fmaxf(sqrtf(ss), 1e-12f);
        #pragma unroll
        for (int t = 0; t < 4; ++t) {
            float mu = m4[t] * inv_norm;
            float lv = tanhf(l4[t]);
            float iv = expf(-lv);
            float diff2 = fmaf(mu, mu, fmaf(-2.f * mu, ebv[t], eb2v[t]));
            wacc += fmaf(diff2, iv, lv);
        }
    }
    #pragma unroll
    for (int o = 32; o > 0; o >>= 1) wacc += __shfl_xor(wacc, o, 64);
    if (lane == 0) atomicAdd(bsum, wacc);
    __syncthreads();
    if (tid == 0) {
        atomicAdd(p.acc, *bsum);
        asm volatile("s_waitcnt vmcnt(0)" ::: "memory");
        unsigned prev = __hip_atomic_fetch_add(p.done, 1u, __ATOMIC_RELAXED,
                                               __HIP_MEMORY_SCOPE_AGENT);
        if (prev == 31u) {
            float v = __hip_atomic_load(p.acc, __ATOMIC_RELAXED, __HIP_MEMORY_SCOPE_AGENT);
            p.out[0] = v * (1.0f / (float)N_ROWS);
        }
    }
}

extern "C" void kernel_launch(void* const* d_in, const int* in_sizes, int n_in,
                              void* d_out, int out_size, void* d_ws, size_t ws_size,
                              hipStream_t stream) {
    Params p;
    p.a = (const float*)d_in[0];
    p.b = (const float*)d_in[1];
    p.w[0] = (const float*)d_in[2];  p.bias[0] = (const float*)d_in[3];   // mu L0
    p.w[2] = (const float*)d_in[4];  p.bias[2] = (const float*)d_in[5];   // mu L1
    p.w[4] = (const float*)d_in[6];  p.bias[4] = (const float*)d_in[7];   // mu L2
    p.w[1] = (const float*)d_in[8];  p.bias[1] = (const float*)d_in[9];   // lv L0
    p.w[3] = (const float*)d_in[10]; p.bias[3] = (const float*)d_in[11];  // lv L1
    p.w[5] = (const float*)d_in[12]; p.bias[5] = (const float*)d_in[13];  // lv L2

    float* f = (float*)d_ws;
    p.flags  = (unsigned*)f;            // [0..31]
    p.acc    = f + 32;
    p.done   = (unsigned*)(f + 33);
    p.ebsum  = f + 64;                  // [64..319]
    p.eb2sum = f + 320;                 // [320..575]
    p.g_mu   = f + 1024;                // 1024*256 f32
    half_t* hb = (half_t*)(p.g_mu + N_ROWS * DIM);
    p.wt[0] = hb;  hb += HID * DIM;
    p.wt[1] = hb;  hb += HID * DIM;
    p.wt[2] = hb;  hb += HID * HID;
    p.wt[3] = hb;  hb += HID * HID;
    p.wt[4] = hb;  hb += DIM * HID;
    p.wt[5] = hb;  hb += DIM * HID;
    p.out   = (float*)d_out;

    hipMemsetAsync(d_ws, 0, 4096, stream);   // flags + acc + done + ebsum + eb2sum
    prep_kernel<<<dim3(256, 7), 256, 0, stream>>>(p);
    main_kernel<<<64, 512, 0, stream>>>(p);
}

// Round 11
// 35.184 us; speedup vs baseline: 1.5215x; 1.5215x over previous
//
#include <hip/hip_runtime.h>
#include <hip/hip_fp16.h>

#define N_ROWS 1024
#define DIM 256
#define HID 512

typedef _Float16 half_t;
typedef __attribute__((ext_vector_type(8))) _Float16 half8v;
typedef __attribute__((ext_vector_type(16))) float f32x16;

struct Params {
    const float* a;
    const float* b;
    const float* w[6];      // w0m,w0l,w1m,w1l,w2m,w2l (fp32, K x N)
    const float* bias[6];
    unsigned* flags;        // [32], single producer each, target 1
    float* acc;
    unsigned* done;         // target 32
    float* ebsum;           // [256]
    float* eb2sum;          // [256]
    float* g_mu;            // [1024][256] f32 handoff
    half_t* wt[6];          // fragment-packed f16 weights
    float* out;
};

// ---------------- prep: pack W into MFMA fragment order + colstats ----------------
// packed layout (halves): ((t*C + c)*2 + which)*512 + (hi*32 + lr)*8 + e
//   t = n>>5 (col tile), c = k>>5 (k chunk), r = k&31, which = r>>4,
//   hi = (r>>3)&1, e = r&7, lr = n&31.
__global__ __launch_bounds__(256) void prep_kernel(Params p) {
    const int y = blockIdx.y, bx = blockIdx.x, tid = threadIdx.x;

    if (y == 6) {           // colstats: 64 blocks x 16 rows
        if (bx >= 64) return;
        const int d = tid, r0 = bx * 16;
        float s = 0.f, s2 = 0.f;
        #pragma unroll
        for (int r = 0; r < 16; ++r) {
            float v = p.b[(r0 + r) * DIM + d];
            s += v; s2 = fmaf(v, v, s2);
        }
        atomicAdd(&p.ebsum[d], s);
        atomicAdd(&p.eb2sum[d], s2);
        return;
    }
    const float* src = p.w[y];
    half_t* dst = p.wt[y];
    const int K = (y < 2) ? DIM : HID;
    const int N = (y < 4) ? HID : DIM;
    const int C = K >> 5;
    const int ntiles = (K >> 5) * (N >> 5);        // 32x32 element tiles
    if (bx >= ntiles) return;
    const int tilesN = N >> 5;
    const int tk = bx / tilesN, tn = bx % tilesN;  // tk = chunk c, tn = col tile t
    const int r = tid >> 3, c4 = (tid & 7) * 4;    // r = k in tile, c4 = n offset
    float4 v = *(const float4*)&src[(tk * 32 + r) * N + tn * 32 + c4];
    const int which = r >> 4, hi = (r >> 3) & 1, e = r & 7;
    half_t* base = dst + ((tn * C + tk) * 2 + which) * 512 + hi * 256 + e;
    base[(c4 + 0) * 8] = (half_t)v.x;
    base[(c4 + 1) * 8] = (half_t)v.y;
    base[(c4 + 2) * 8] = (half_t)v.z;
    base[(c4 + 3) * 8] = (half_t)v.w;
}

// ---------------- one layer: A in LDS (chunk-swizzled), W fragment-packed ----
// Xin: LDS [NC][32][40] f16. Wfrag: packed global. 8 waves, NT col-tiles
// interleaved (shared A reads, independent acc chains).
// MODE 0: relu -> Xout LDS (chunk layout). MODE 1: f32 -> gmu (agent).
// MODE 2: f32 -> rawL LDS [32][256].
template <int NC, int NT, int MODE>
__device__ __forceinline__ void gemm_layer(const half_t* __restrict__ Xin,
                                           const half_t* __restrict__ Wfrag,
                                           const float* __restrict__ bias,
                                           half_t* __restrict__ Xout,
                                           float* __restrict__ rawL,
                                           float* __restrict__ gmu,
                                           const int R0) {
    const int tid = threadIdx.x;
    const int w = tid >> 6, lane = tid & 63;
    const int lr = lane & 31, hi = lane >> 5;
    const int sa = (lr >> 3) & 3;
    const int aoff0 = lr * 40 + ((hi ^ sa) * 8);
    const int aoff1 = lr * 40 + (((hi + 2) ^ sa) * 8);

    // per-tile packed W base: frag + t*NC*1024 + lane*8
    const half_t* Wp[NT];
    #pragma unroll
    for (int ct = 0; ct < NT; ++ct)
        Wp[ct] = Wfrag + (w * NT + ct) * NC * 1024 + lane * 8;

    f32x16 acc[NT];
    #pragma unroll
    for (int ct = 0; ct < NT; ++ct)
        #pragma unroll
        for (int i = 0; i < 16; ++i) acc[ct][i] = 0.f;

    half8v wbuf[NT][4][2], abuf[2][2];
    #define ISSUE_W(ct, c)                                                    \
        do {                                                                  \
            wbuf[ct][(c) & 3][0] = *(const half8v*)(Wp[ct] + (c) * 1024);     \
            wbuf[ct][(c) & 3][1] = *(const half8v*)(Wp[ct] + (c) * 1024 + 512);\
        } while (0)
    #define ISSUE_A(c)                                                        \
        do {                                                                  \
            abuf[(c) & 1][0] = *(const half8v*)&Xin[(c) * 1280 + aoff0];      \
            abuf[(c) & 1][1] = *(const half8v*)&Xin[(c) * 1280 + aoff1];      \
        } while (0)

    #pragma unroll
    for (int c = 0; c < 4 && c < NC; ++c) {
        #pragma unroll
        for (int ct = 0; ct < NT; ++ct) ISSUE_W(ct, c);
    }
    ISSUE_A(0);
    if (NC > 1) ISSUE_A(1);

    #pragma unroll
    for (int c = 0; c < NC; ++c) {
        half8v av0 = abuf[c & 1][0], av1 = abuf[c & 1][1];
        if (c + 2 < NC) ISSUE_A(c + 2);
        #pragma unroll
        for (int ct = 0; ct < NT; ++ct) {
            half8v bv0 = wbuf[ct][c & 3][0], bv1 = wbuf[ct][c & 3][1];
            if (c + 4 < NC) ISSUE_W(ct, c + 4);
            acc[ct] = __builtin_amdgcn_mfma_f32_32x32x16_f16(av0, bv0, acc[ct], 0, 0, 0);
            acc[ct] = __builtin_amdgcn_mfma_f32_32x32x16_f16(av1, bv1, acc[ct], 0, 0, 0);
        }
    }
    #undef ISSUE_W
    #undef ISSUE_A

    // epilogue: C/D layout col = lane&31, row = (reg&3)+8*(reg>>2)+4*(lane>>5)
    #pragma unroll
    for (int ct = 0; ct < NT; ++ct) {
        const int col0 = (w * NT + ct) * 32;
        const int col = col0 + lr;
        const float bv = bias[col];
        #pragma unroll
        for (int r = 0; r < 16; ++r) {
            const int row = (r & 3) + 8 * (r >> 2) + 4 * hi;
            float v = acc[ct][r] + bv;
            if (MODE == 0) {
                v = fmaxf(v, 0.f);
                const int kbp = (lr >> 3) ^ ((row >> 3) & 3);
                Xout[(col0 >> 5) * 1280 + row * 40 + kbp * 8 + (lr & 7)] = (half_t)v;
            } else if (MODE == 1) {
                __hip_atomic_store(&gmu[(R0 + row) * DIM + col], v,
                                   __ATOMIC_RELAXED, __HIP_MEMORY_SCOPE_AGENT);
            } else {
                rawL[row * 256 + col] = v;
            }
        }
    }
}

// ---------------- main: 64 blocks, whole net per block, 1 sync hop total ----
__global__ void __launch_bounds__(512) main_kernel(Params p) {
    __shared__ alignas(16) char smem[81984];
    half_t* XA = (half_t*)smem;                 // [16][32][40]
    half_t* XB = (half_t*)(smem + 40960);       // [16][32][40]
    float* rawL = (float*)(smem + 40960);       // [32][256] f32 (XB region, L2 phase)
    float* bsum = (float*)(smem + 81920);

    const int bid = blockIdx.x, tid = threadIdx.x;
    const int net = bid & 1, g = bid >> 1, R0 = g * 32;

    // ---- stage a rows -> XA chunks (fp32 -> f16, swizzled) ----
    {
        const int r = tid >> 4, q = tid & 15;
        const float* src = &p.a[(R0 + r) * DIM + q * 16];
        float4 v0 = *(const float4*)(src);
        float4 v1 = *(const float4*)(src + 4);
        float4 v2 = *(const float4*)(src + 8);
        float4 v3 = *(const float4*)(src + 12);
        half8v h0, h1;
        h0[0] = (half_t)v0.x; h0[1] = (half_t)v0.y; h0[2] = (half_t)v0.z; h0[3] = (half_t)v0.w;
        h0[4] = (half_t)v1.x; h0[5] = (half_t)v1.y; h0[6] = (half_t)v1.z; h0[7] = (half_t)v1.w;
        h1[0] = (half_t)v2.x; h1[1] = (half_t)v2.y; h1[2] = (half_t)v2.z; h1[3] = (half_t)v2.w;
        h1[4] = (half_t)v3.x; h1[5] = (half_t)v3.y; h1[6] = (half_t)v3.z; h1[7] = (half_t)v3.w;
        const int c = q >> 1, kb0 = (q & 1) * 2, s = (r >> 3) & 3;
        *(half8v*)&XA[c * 1280 + r * 40 + ((kb0 ^ s) * 8)] = h0;
        *(half8v*)&XA[c * 1280 + r * 40 + (((kb0 + 1) ^ s) * 8)] = h1;
    }
    __syncthreads();

    // ---- L0: XA(a) @ wt[net] -> XB (h1, relu), 512 cols ----
    gemm_layer<8, 2, 0>(XA, p.wt[net], p.bias[net], XB, nullptr, nullptr, R0);
    __syncthreads();
    // ---- L1: XB(h1) @ wt[2+net] -> XA (h2, relu), 512 cols ----
    gemm_layer<16, 2, 0>(XB, p.wt[2 + net], p.bias[2 + net], XA, nullptr, nullptr, R0);
    __syncthreads();

    if (net == 0) {
        // ---- L2 mu: XA(h2) @ wt[4] -> g_mu (f32, agent stores), 256 cols ----
        gemm_layer<16, 1, 1>(XA, p.wt[4], p.bias[4], nullptr, nullptr, p.g_mu, R0);
        asm volatile("s_waitcnt vmcnt(0)" ::: "memory");
        __syncthreads();
        if (tid == 0)
            __hip_atomic_store(&p.flags[g], 1u, __ATOMIC_RELAXED, __HIP_MEMORY_SCOPE_AGENT);
        return;
    }

    // ---- L2 lv: XA(h2) @ wt[5] -> rawL (LDS f32), 256 cols ----
    gemm_layer<16, 1, 2>(XA, p.wt[5], p.bias[5], nullptr, rawL, nullptr, R0);
    if (tid == 0) *bsum = 0.f;
    if (tid == 0) {
        while (__hip_atomic_load(&p.flags[g], __ATOMIC_RELAXED, __HIP_MEMORY_SCOPE_AGENT) == 0u)
            __builtin_amdgcn_s_sleep(1);
    }
    __syncthreads();
    asm volatile("" ::: "memory");

    // ---- loss for rows R0..R0+31 (8 waves x 4 rows) ----
    const int wave = tid >> 6, lane = tid & 63;
    const float invN = 1.0f / (float)N_ROWS;
    float ebv[4], eb2v[4];
    #pragma unroll
    for (int t = 0; t < 4; ++t) {
        const int d = lane + t * 64;
        ebv[t]  = p.ebsum[d] * invN;
        eb2v[t] = p.eb2sum[d] * invN;
    }
    float wacc = 0.f;
    #pragma unroll
    for (int rr = 0; rr < 4; ++rr) {
        const int i = wave * 4 + rr;
        float m4[4], l4[4], ss = 0.f;
        #pragma unroll
        for (int t = 0; t < 4; ++t) {
            const int d = lane + t * 64;
            m4[t] = p.g_mu[(R0 + i) * DIM + d];
            l4[t] = rawL[i * 256 + d];
            ss = fmaf(m4[t], m4[t], ss);
        }
        #pragma unroll
        for (int o = 32; o > 0; o >>= 1) ss += __shfl_xor(ss, o, 64);
        const float inv_norm = 1.f / fmaxf(sqrtf(ss), 1e-12f);
        #pragma unroll
        for (int t = 0; t < 4; ++t) {
            float mu = m4[t] * inv_norm;
            float lv = tanhf(l4[t]);
            float iv = expf(-lv);
            float diff2 = fmaf(mu, mu, fmaf(-2.f * mu, ebv[t], eb2v[t]));
            wacc += fmaf(diff2, iv, lv);
        }
    }
    #pragma unroll
    for (int o = 32; o > 0; o >>= 1) wacc += __shfl_xor(wacc, o, 64);
    if (lane == 0) atomicAdd(bsum, wacc);
    __syncthreads();
    if (tid == 0) {
        atomicAdd(p.acc, *bsum);
        asm volatile("s_waitcnt vmcnt(0)" ::: "memory");
        unsigned prev = __hip_atomic_fetch_add(p.done, 1u, __ATOMIC_RELAXED,
                                               __HIP_MEMORY_SCOPE_AGENT);
        if (prev == 31u) {
            float v = __hip_atomic_load(p.acc, __ATOMIC_RELAXED, __HIP_MEMORY_SCOPE_AGENT);
            p.out[0] = v * (1.0f / (float)N_ROWS);
        }
    }
}

extern "C" void kernel_launch(void* const* d_in, const int* in_sizes, int n_in,
                              void* d_out, int out_size, void* d_ws, size_t ws_size,
                              hipStream_t stream) {
    Params p;
    p.a = (const float*)d_in[0];
    p.b = (const float*)d_in[1];
    p.w[0] = (const float*)d_in[2];  p.bias[0] = (const float*)d_in[3];   // mu L0
    p.w[2] = (const float*)d_in[4];  p.bias[2] = (const float*)d_in[5];   // mu L1
    p.w[4] = (const float*)d_in[6];  p.bias[4] = (const float*)d_in[7];   // mu L2
    p.w[1] = (const float*)d_in[8];  p.bias[1] = (const float*)d_in[9];   // lv L0
    p.w[3] = (const float*)d_in[10]; p.bias[3] = (const float*)d_in[11];  // lv L1
    p.w[5] = (const float*)d_in[12]; p.bias[5] = (const float*)d_in[13];  // lv L2

    float* f = (float*)d_ws;
    p.flags  = (unsigned*)f;            // [0..31]
    p.acc    = f + 32;
    p.done   = (unsigned*)(f + 33);
    p.ebsum  = f + 64;                  // [64..319]
    p.eb2sum = f + 320;                 // [320..575]
    p.g_mu   = f + 1024;                // 1024*256 f32
    half_t* hb = (half_t*)(p.g_mu + N_ROWS * DIM);
    p.wt[0] = hb;  hb += HID * DIM;
    p.wt[1] = hb;  hb += HID * DIM;
    p.wt[2] = hb;  hb += HID * HID;
    p.wt[3] = hb;  hb += HID * HID;
    p.wt[4] = hb;  hb += DIM * HID;
    p.wt[5] = hb;  hb += DIM * HID;
    p.out   = (float*)d_out;

    hipMemsetAsync(d_ws, 0, 4096, stream);   // flags + acc + done + ebsum + eb2sum
    prep_kernel<<<dim3(256, 7), 256, 0, stream>>>(p);
    main_kernel<<<64, 512, 0, stream>>>(p);
}

// Round 12
// 33.903 us; speedup vs baseline: 1.5790x; 1.0378x over previous
//
#include <hip/hip_runtime.h>
#include <hip/hip_fp16.h>

#define N_ROWS 1024
#define DIM 256
#define HID 512

typedef _Float16 half_t;
typedef __attribute__((ext_vector_type(4))) _Float16 half4v;
typedef __attribute__((ext_vector_type(8))) _Float16 half8v;
typedef __attribute__((ext_vector_type(16))) float f32x16;

struct Params {
    const float* a;
    const float* b;
    const float* w[6];      // w0m,w0l,w1m,w1l,w2m,w2l (fp32, K x N)
    const float* bias[6];
    unsigned* flags;        // [32], single producer each, target 1
    float* acc;
    unsigned* done;         // target 32
    float* ebsum;           // [256]
    float* eb2sum;          // [256]
    unsigned short* g_mu;   // [1024][256] f16 handoff (raw mu)
    half_t* wt[6];          // fragment-packed f16 weights
    float* out;
};

// ---------------- prep: pack W into MFMA fragment order (coalesced) + colstats ----
// packed layout (halves): ((t*C + c)*2 + which)*512 + (hi*32 + lr)*8 + e
//   value = W[c*32 + which*16 + hi*8 + e][t*32 + lr]
__global__ __launch_bounds__(256) void prep_kernel(Params p) {
    const int y = blockIdx.y, bx = blockIdx.x, tid = threadIdx.x;

    if (y == 6) {           // colstats: 64 blocks x 16 rows
        if (bx >= 64) return;
        const int d = tid, r0 = bx * 16;
        float s = 0.f, s2 = 0.f;
        #pragma unroll
        for (int r = 0; r < 16; ++r) {
            float v = p.b[(r0 + r) * DIM + d];
            s += v; s2 = fmaf(v, v, s2);
        }
        atomicAdd(&p.ebsum[d], s);
        atomicAdd(&p.eb2sum[d], s2);
        return;
    }
    __shared__ float T[32][33];
    const float* src = p.w[y];
    half_t* dst = p.wt[y];
    const int K = (y < 2) ? DIM : HID;
    const int N = (y < 4) ? HID : DIM;
    const int C = K >> 5;
    const int tilesN = N >> 5;
    if (bx >= C * tilesN) return;
    const int tk = bx / tilesN, tn = bx % tilesN;   // k-chunk, col-tile

    {   // coalesced fp32 tile read -> LDS
        const int r = tid >> 3, c4 = (tid & 7) * 4;
        float4 v = *(const float4*)&src[(tk * 32 + r) * N + tn * 32 + c4];
        T[r][c4 + 0] = v.x; T[r][c4 + 1] = v.y; T[r][c4 + 2] = v.z; T[r][c4 + 3] = v.w;
    }
    __syncthreads();

    // fragment gather: 8B contiguous per thread, wave-contiguous writes
    const int which = tid >> 7;             // 0..1
    const int lane64 = (tid >> 1) & 63;
    const int epart = tid & 1;              // low/high 4 halves
    const int hi = lane64 >> 5, lr = lane64 & 31;
    const int rbase = which * 16 + hi * 8 + epart * 4;
    half4v h;
    h[0] = (half_t)T[rbase + 0][lr];
    h[1] = (half_t)T[rbase + 1][lr];
    h[2] = (half_t)T[rbase + 2][lr];
    h[3] = (half_t)T[rbase + 3][lr];
    *(half4v*)&dst[((tn * C + tk) * 2 + which) * 512 + lane64 * 8 + epart * 4] = h;
}

// ---------------- one layer: A in LDS (chunk-swizzled), W fragment-packed ----
// Xin: LDS [NC][32][40] f16. Wfrag: packed global. 8 waves, NT col-tiles
// interleaved. MODE 0: relu -> Xout LDS (chunk layout). MODE 1: f16 -> gmu
// (agent). MODE 2: f32 -> rawL LDS [32][256].
template <int NC, int NT, int MODE>
__device__ __forceinline__ void gemm_layer(const half_t* __restrict__ Xin,
                                           const half_t* __restrict__ Wfrag,
                                           const float* __restrict__ bias,
                                           half_t* __restrict__ Xout,
                                           float* __restrict__ rawL,
                                           unsigned short* __restrict__ gmu,
                                           const int R0) {
    const int tid = threadIdx.x;
    const int w = tid >> 6, lane = tid & 63;
    const int lr = lane & 31, hi = lane >> 5;
    const int sa = (lr >> 3) & 3;
    const int aoff0 = lr * 40 + ((hi ^ sa) * 8);
    const int aoff1 = lr * 40 + (((hi + 2) ^ sa) * 8);
    constexpr int PFW = (NC < 6) ? NC : 6;      // W prefetch depth

    const half_t* Wp[NT];
    #pragma unroll
    for (int ct = 0; ct < NT; ++ct)
        Wp[ct] = Wfrag + (w * NT + ct) * NC * 1024 + lane * 8;

    f32x16 acc[NT];
    #pragma unroll
    for (int ct = 0; ct < NT; ++ct)
        #pragma unroll
        for (int i = 0; i < 16; ++i) acc[ct][i] = 0.f;

    half8v wbuf[NT][6][2], abuf[2][2];
    #define ISSUE_W(ct, c)                                                     \
        do {                                                                   \
            wbuf[ct][(c) % 6][0] = *(const half8v*)(Wp[ct] + (c) * 1024);      \
            wbuf[ct][(c) % 6][1] = *(const half8v*)(Wp[ct] + (c) * 1024 + 512);\
        } while (0)
    #define ISSUE_A(c)                                                         \
        do {                                                                   \
            abuf[(c) & 1][0] = *(const half8v*)&Xin[(c) * 1280 + aoff0];       \
            abuf[(c) & 1][1] = *(const half8v*)&Xin[(c) * 1280 + aoff1];       \
        } while (0)

    #pragma unroll
    for (int c = 0; c < PFW; ++c) {
        #pragma unroll
        for (int ct = 0; ct < NT; ++ct) ISSUE_W(ct, c);
    }
    ISSUE_A(0);
    if (NC > 1) ISSUE_A(1);

    #pragma unroll
    for (int c = 0; c < NC; ++c) {
        half8v av0 = abuf[c & 1][0], av1 = abuf[c & 1][1];
        if (c + 2 < NC) ISSUE_A(c + 2);
        #pragma unroll
        for (int ct = 0; ct < NT; ++ct) {
            half8v bv0 = wbuf[ct][c % 6][0], bv1 = wbuf[ct][c % 6][1];
            if (c + PFW < NC) ISSUE_W(ct, c + PFW);
            acc[ct] = __builtin_amdgcn_mfma_f32_32x32x16_f16(av0, bv0, acc[ct], 0, 0, 0);
            acc[ct] = __builtin_amdgcn_mfma_f32_32x32x16_f16(av1, bv1, acc[ct], 0, 0, 0);
        }
    }
    #undef ISSUE_W
    #undef ISSUE_A

    // epilogue: C/D layout col = lane&31, row = (reg&3)+8*(reg>>2)+4*(lane>>5)
    #pragma unroll
    for (int ct = 0; ct < NT; ++ct) {
        const int col0 = (w * NT + ct) * 32;
        const int col = col0 + lr;
        const float bv = bias[col];
        #pragma unroll
        for (int r = 0; r < 16; ++r) {
            const int row = (r & 3) + 8 * (r >> 2) + 4 * hi;
            float v = acc[ct][r] + bv;
            if (MODE == 0) {
                v = fmaxf(v, 0.f);
                const int kbp = (lr >> 3) ^ ((row >> 3) & 3);
                Xout[(col0 >> 5) * 1280 + row * 40 + kbp * 8 + (lr & 7)] = (half_t)v;
            } else if (MODE == 1) {
                union { half_t h; unsigned short u; } cv;
                cv.h = (half_t)v;
                __hip_atomic_store(&gmu[(R0 + row) * DIM + col], cv.u,
                                   __ATOMIC_RELAXED, __HIP_MEMORY_SCOPE_AGENT);
            } else {
                rawL[row * 256 + col] = v;
            }
        }
    }
}

// ---------------- main: 64 blocks, whole net per block, 1 sync hop total ----
__global__ void __launch_bounds__(512) main_kernel(Params p) {
    __shared__ alignas(16) char smem[81984];
    half_t* XA = (half_t*)smem;                 // [16][32][40]
    half_t* XB = (half_t*)(smem + 40960);       // [16][32][40]
    float* rawL = (float*)(smem + 40960);       // [32][256] f32 (XB region, L2 phase)
    float* bsum = (float*)(smem + 81920);

    const int bid = blockIdx.x, tid = threadIdx.x;
    const int net = bid & 1, g = bid >> 1, R0 = g * 32;

    // ---- stage a rows -> XA chunks (fp32 -> f16, swizzled) ----
    {
        const int r = tid >> 4, q = tid & 15;
        const float* src = &p.a[(R0 + r) * DIM + q * 16];
        float4 v0 = *(const float4*)(src);
        float4 v1 = *(const float4*)(src + 4);
        float4 v2 = *(const float4*)(src + 8);
        float4 v3 = *(const float4*)(src + 12);
        half8v h0, h1;
        h0[0] = (half_t)v0.x; h0[1] = (half_t)v0.y; h0[2] = (half_t)v0.z; h0[3] = (half_t)v0.w;
        h0[4] = (half_t)v1.x; h0[5] = (half_t)v1.y; h0[6] = (half_t)v1.z; h0[7] = (half_t)v1.w;
        h1[0] = (half_t)v2.x; h1[1] = (half_t)v2.y; h1[2] = (half_t)v2.z; h1[3] = (half_t)v2.w;
        h1[4] = (half_t)v3.x; h1[5] = (half_t)v3.y; h1[6] = (half_t)v3.z; h1[7] = (half_t)v3.w;
        const int c = q >> 1, kb0 = (q & 1) * 2, s = (r >> 3) & 3;
        *(half8v*)&XA[c * 1280 + r * 40 + ((kb0 ^ s) * 8)] = h0;
        *(half8v*)&XA[c * 1280 + r * 40 + (((kb0 + 1) ^ s) * 8)] = h1;
    }
    __syncthreads();

    // ---- L0: XA(a) @ wt[net] -> XB (h1, relu), 512 cols ----
    gemm_layer<8, 2, 0>(XA, p.wt[net], p.bias[net], XB, nullptr, nullptr, R0);
    __syncthreads();
    // ---- L1: XB(h1) @ wt[2+net] -> XA (h2, relu), 512 cols ----
    gemm_layer<16, 2, 0>(XB, p.wt[2 + net], p.bias[2 + net], XA, nullptr, nullptr, R0);
    __syncthreads();

    if (net == 0) {
        // ---- L2 mu: XA(h2) @ wt[4] -> g_mu (f16, agent stores), 256 cols ----
        gemm_layer<16, 1, 1>(XA, p.wt[4], p.bias[4], nullptr, nullptr, p.g_mu, R0);
        asm volatile("s_waitcnt vmcnt(0)" ::: "memory");
        __syncthreads();
        if (tid == 0)
            __hip_atomic_store(&p.flags[g], 1u, __ATOMIC_RELAXED, __HIP_MEMORY_SCOPE_AGENT);
        return;
    }

    // ---- L2 lv: XA(h2) @ wt[5] -> rawL (LDS f32), 256 cols ----
    gemm_layer<16, 1, 2>(XA, p.wt[5], p.bias[5], nullptr, rawL, nullptr, R0);
    if (tid == 0) *bsum = 0.f;
    if (tid == 0) {
        while (__hip_atomic_load(&p.flags[g], __ATOMIC_RELAXED, __HIP_MEMORY_SCOPE_AGENT) == 0u)
            __builtin_amdgcn_s_sleep(1);
    }
    __syncthreads();
    asm volatile("" ::: "memory");

    // ---- loss for rows R0..R0+31 (8 waves x 4 rows) ----
    const int wave = tid >> 6, lane = tid & 63;
    const float invN = 1.0f / (float)N_ROWS;
    float ebv[4], eb2v[4];
    #pragma unroll
    for (int t = 0; t < 4; ++t) {
        const int d = lane + t * 64;
        ebv[t]  = p.ebsum[d] * invN;
        eb2v[t] = p.eb2sum[d] * invN;
    }
    float wacc = 0.f;
    #pragma unroll
    for (int rr = 0; rr < 4; ++rr) {
        const int i = wave * 4 + rr;
        float m4[4], l4[4], ss = 0.f;
        #pragma unroll
        for (int t = 0; t < 4; ++t) {
            const int d = lane + t * 64;
            unsigned short mu_u = __hip_atomic_load(&p.g_mu[(R0 + i) * DIM + d],
                                                    __ATOMIC_RELAXED, __HIP_MEMORY_SCOPE_AGENT);
            union { unsigned short u; half_t h; } cv;
            cv.u = mu_u;
            m4[t] = (float)cv.h;
            l4[t] = rawL[i * 256 + d];
            ss = fmaf(m4[t], m4[t], ss);
        }
        #pragma unroll
        for (int o = 32; o > 0; o >>= 1) ss += __shfl_xor(ss, o, 64);
        const float inv_norm = 1.f / fmaxf(sqrtf(ss), 1e-12f);
        #pragma unroll
        for (int t = 0; t < 4; ++t) {
            float mu = m4[t] * inv_norm;
            float lv = tanhf(l4[t]);
            float iv = expf(-lv);
            float diff2 = fmaf(mu, mu, fmaf(-2.f * mu, ebv[t], eb2v[t]));
            wacc += fmaf(diff2, iv, lv);
        }
    }
    #pragma unroll
    for (int o = 32; o > 0; o >>= 1) wacc += __shfl_xor(wacc, o, 64);
    if (lane == 0) atomicAdd(bsum, wacc);
    __syncthreads();
    if (tid == 0) {
        atomicAdd(p.acc, *bsum);
        asm volatile("s_waitcnt vmcnt(0)" ::: "memory");
        unsigned prev = __hip_atomic_fetch_add(p.done, 1u, __ATOMIC_RELAXED,
                                               __HIP_MEMORY_SCOPE_AGENT);
        if (prev == 31u) {
            float v = __hip_atomic_load(p.acc, __ATOMIC_RELAXED, __HIP_MEMORY_SCOPE_AGENT);
            p.out[0] = v * (1.0f / (float)N_ROWS);
        }
    }
}

extern "C" void kernel_launch(void* const* d_in, const int* in_sizes, int n_in,
                              void* d_out, int out_size, void* d_ws, size_t ws_size,
                              hipStream_t stream) {
    Params p;
    p.a = (const float*)d_in[0];
    p.b = (const float*)d_in[1];
    p.w[0] = (const float*)d_in[2];  p.bias[0] = (const float*)d_in[3];   // mu L0
    p.w[2] = (const float*)d_in[4];  p.bias[2] = (const float*)d_in[5];   // mu L1
    p.w[4] = (const float*)d_in[6];  p.bias[4] = (const float*)d_in[7];   // mu L2
    p.w[1] = (const float*)d_in[8];  p.bias[1] = (const float*)d_in[9];   // lv L0
    p.w[3] = (const float*)d_in[10]; p.bias[3] = (const float*)d_in[11];  // lv L1
    p.w[5] = (const float*)d_in[12]; p.bias[5] = (const float*)d_in[13];  // lv L2

    float* f = (float*)d_ws;
    p.flags  = (unsigned*)f;            // [0..31]
    p.acc    = f + 32;
    p.done   = (unsigned*)(f + 33);
    p.ebsum  = f + 64;                  // [64..319]
    p.eb2sum = f + 320;                 // [320..575]
    p.g_mu   = (unsigned short*)(f + 1024);   // 1024*256 f16
    half_t* hb = (half_t*)(p.g_mu + N_ROWS * DIM);
    p.wt[0] = hb;  hb += HID * DIM;
    p.wt[1] = hb;  hb += HID * DIM;
    p.wt[2] = hb;  hb += HID * HID;
    p.wt[3] = hb;  hb += HID * HID;
    p.wt[4] = hb;  hb += DIM * HID;
    p.wt[5] = hb;  hb += DIM * HID;
    p.out   = (float*)d_out;

    hipMemsetAsync(d_ws, 0, 4096, stream);   // flags + acc + done + ebsum + eb2sum
    prep_kernel<<<dim3(256, 7), 256, 0, stream>>>(p);
    main_kernel<<<64, 512, 0, stream>>>(p);
}

// Round 13
// 31.166 us; speedup vs baseline: 1.7176x; 1.0878x over previous
//
#include <hip/hip_runtime.h>
#include <hip/hip_fp16.h>

#define N_ROWS 1024
#define DIM 256
#define HID 512
#define CTR 16          // uints per counter (64B stride)

typedef _Float16 half_t;
typedef __attribute__((ext_vector_type(4))) _Float16 half4v;
typedef __attribute__((ext_vector_type(8))) _Float16 half8v;
typedef __attribute__((ext_vector_type(16))) float f32x16;

struct Params {
    const float* a;
    const float* b;
    const float* w[6];      // fp32 K x N
    const float* bias[6];
    unsigned* c1;           // 64 counters (net*32+g), target 4
    unsigned* c2;           // 64 counters, target 4
    unsigned* c3;           // 32 counters (g), target 8
    float* acc;
    unsigned* done;         // target 128
    float* ebsum;           // [256]
    float* eb2sum;          // [256]
    unsigned short* g_mu;   // [1024][256] f16
    unsigned short* g_lv;   // [1024][256] f16
    half_t* g_h1[2];        // [1024][512] f16
    half_t* g_h2[2];        // [1024][512] f16
    half_t* wt[6];          // fragment-packed f16 weights
    float* out;
};

// ---------------- prep: pack W into MFMA fragment order + colstats (r12 proven) ----
__global__ __launch_bounds__(256) void prep_kernel(Params p) {
    const int y = blockIdx.y, bx = blockIdx.x, tid = threadIdx.x;

    if (y == 6) {           // colstats
        if (bx >= 64) return;
        const int d = tid, r0 = bx * 16;
        float s = 0.f, s2 = 0.f;
        #pragma unroll
        for (int r = 0; r < 16; ++r) {
            float v = p.b[(r0 + r) * DIM + d];
            s += v; s2 = fmaf(v, v, s2);
        }
        atomicAdd(&p.ebsum[d], s);
        atomicAdd(&p.eb2sum[d], s2);
        return;
    }
    __shared__ float T[32][33];
    const float* src = p.w[y];
    half_t* dst = p.wt[y];
    const int K = (y < 2) ? DIM : HID;
    const int N = (y < 4) ? HID : DIM;
    const int C = K >> 5;
    const int tilesN = N >> 5;
    if (bx >= C * tilesN) return;
    const int tk = bx / tilesN, tn = bx % tilesN;

    {
        const int r = tid >> 3, c4 = (tid & 7) * 4;
        float4 v = *(const float4*)&src[(tk * 32 + r) * N + tn * 32 + c4];
        T[r][c4 + 0] = v.x; T[r][c4 + 1] = v.y; T[r][c4 + 2] = v.z; T[r][c4 + 3] = v.w;
    }
    __syncthreads();
    const int which = tid >> 7;
    const int lane64 = (tid >> 1) & 63;
    const int epart = tid & 1;
    const int hi = lane64 >> 5, lr = lane64 & 31;
    const int rbase = which * 16 + hi * 8 + epart * 4;
    half4v h;
    h[0] = (half_t)T[rbase + 0][lr];
    h[1] = (half_t)T[rbase + 1][lr];
    h[2] = (half_t)T[rbase + 2][lr];
    h[3] = (half_t)T[rbase + 3][lr];
    *(half4v*)&dst[((tn * C + tk) * 2 + which) * 512 + lane64 * 8 + epart * 4] = h;
}

// ---------------- flag sync (r6-r12 proven) ----------------
__device__ __forceinline__ void flag_add(unsigned* c) {
    asm volatile("s_waitcnt vmcnt(0)" ::: "memory");
    __syncthreads();
    if (threadIdx.x == 0)
        __hip_atomic_fetch_add(c, 1u, __ATOMIC_RELAXED, __HIP_MEMORY_SCOPE_AGENT);
}
__device__ __forceinline__ void flag_wait(unsigned* c, unsigned tgt) {
    if (threadIdx.x == 0) {
        while (__hip_atomic_load(c, __ATOMIC_RELAXED, __HIP_MEMORY_SCOPE_AGENT) < tgt)
            __builtin_amdgcn_s_sleep(1);
    }
    __syncthreads();
    asm volatile("" ::: "memory");
}

// ---------------- one wave's MFMA run over KC chunks of one col-tile ----------
template <int KC>
__device__ __forceinline__ f32x16 mma_tile(const half_t* __restrict__ XA,
                                           const half_t* __restrict__ Wfrag,
                                           const int NCtot, const int tile,
                                           const int k0, const int lane) {
    const int lr = lane & 31, hi = lane >> 5;
    const int sa = (lr >> 3) & 3;
    const int aoff0 = lr * 40 + ((hi ^ sa) * 8);
    const int aoff1 = lr * 40 + (((hi + 2) ^ sa) * 8);
    const half_t* Wp = Wfrag + (tile * NCtot + k0) * 1024 + lane * 8;
    const half_t* Ap = XA + k0 * 1280;
    f32x16 acc;
    #pragma unroll
    for (int i = 0; i < 16; ++i) acc[i] = 0.f;
    #pragma unroll
    for (int c = 0; c < KC; ++c) {
        half8v av0 = *(const half8v*)&Ap[c * 1280 + aoff0];
        half8v av1 = *(const half8v*)&Ap[c * 1280 + aoff1];
        half8v bv0 = *(const half8v*)(Wp + c * 1024);
        half8v bv1 = *(const half8v*)(Wp + c * 1024 + 512);
        acc = __builtin_amdgcn_mfma_f32_32x32x16_f16(av0, bv0, acc, 0, 0, 0);
        acc = __builtin_amdgcn_mfma_f32_32x32x16_f16(av1, bv1, acc, 0, 0, 0);
    }
    return acc;
}

// ---------------- stage helpers ----------------
__device__ __forceinline__ void stage_a(const float* __restrict__ a, half_t* XA,
                                        const int R0, const int tid) {
    const int r = tid >> 4, q = tid & 15;
    const float* src = &a[(R0 + r) * DIM + q * 16];
    float4 v0 = *(const float4*)(src);
    float4 v1 = *(const float4*)(src + 4);
    float4 v2 = *(const float4*)(src + 8);
    float4 v3 = *(const float4*)(src + 12);
    half8v h0, h1;
    h0[0] = (half_t)v0.x; h0[1] = (half_t)v0.y; h0[2] = (half_t)v0.z; h0[3] = (half_t)v0.w;
    h0[4] = (half_t)v1.x; h0[5] = (half_t)v1.y; h0[6] = (half_t)v1.z; h0[7] = (half_t)v1.w;
    h1[0] = (half_t)v2.x; h1[1] = (half_t)v2.y; h1[2] = (half_t)v2.z; h1[3] = (half_t)v2.w;
    h1[4] = (half_t)v3.x; h1[5] = (half_t)v3.y; h1[6] = (half_t)v3.z; h1[7] = (half_t)v3.w;
    const int c = q >> 1, kb0 = (q & 1) * 2, sr = (r >> 3) & 3;
    *(half8v*)&XA[c * 1280 + r * 40 + ((kb0 ^ sr) * 8)] = h0;
    *(half8v*)&XA[c * 1280 + r * 40 + (((kb0 + 1) ^ sr) * 8)] = h1;
}

__device__ __forceinline__ void stage_h(const half_t* __restrict__ src, half_t* XA,
                                        const int R0, const int tid) {
    const int r = tid >> 4, q = tid & 15;       // q = chunk 0..15 (32 cols each)
    const half_t* sp = &src[(R0 + r) * HID + q * 32];
    half8v x0 = *(const half8v*)(sp);
    half8v x1 = *(const half8v*)(sp + 8);
    half8v x2 = *(const half8v*)(sp + 16);
    half8v x3 = *(const half8v*)(sp + 24);
    const int sr = (r >> 3) & 3;
    half_t* d = &XA[q * 1280 + r * 40];
    *(half8v*)&d[(0 ^ sr) * 8] = x0;
    *(half8v*)&d[(1 ^ sr) * 8] = x1;
    *(half8v*)&d[(2 ^ sr) * 8] = x2;
    *(half8v*)&d[(3 ^ sr) * 8] = x3;
}

// ---------------- K-split reduce + epilogue store ----------------
// 2-way: kh==1 wave deposits, kh==0 wave adds + stores.
__device__ __forceinline__ void reduce2_store(f32x16 acc, float* red,
                                              const int tl, const int kh, const int lane,
                                              const float* __restrict__ bias, const int col0,
                                              unsigned short* __restrict__ dstG, const int Nout,
                                              const int R0, const bool relu) {
    __syncthreads();                   // all XA reads done (red overlaps XA)
    if (kh) {
        #pragma unroll
        for (int i = 0; i < 16; ++i) red[tl * 1024 + i * 64 + lane] = acc[i];
    }
    __syncthreads();
    if (!kh) {
        const int lr = lane & 31, hi = lane >> 5;
        const int col = col0 + lr;
        const float bv = bias[col];
        #pragma unroll
        for (int i = 0; i < 16; ++i) {
            float v = acc[i] + red[tl * 1024 + i * 64 + lane] + bv;
            if (relu) v = fmaxf(v, 0.f);
            const int row = (i & 3) + 8 * (i >> 2) + 4 * hi;
            union { half_t h; unsigned short u; } cv; cv.h = (half_t)v;
            __hip_atomic_store(&dstG[(R0 + row) * Nout + col], cv.u,
                               __ATOMIC_RELAXED, __HIP_MEMORY_SCOPE_AGENT);
        }
    }
}

// 4-way: kq 1..3 deposit, kq==0 adds 3 + stores (no relu).
__device__ __forceinline__ void reduce4_store(f32x16 acc, float* red,
                                              const int tl, const int kq, const int lane,
                                              const float* __restrict__ bias, const int col0,
                                              unsigned short* __restrict__ dstG, const int Nout,
                                              const int R0) {
    __syncthreads();
    if (kq) {
        #pragma unroll
        for (int i = 0; i < 16; ++i)
            red[(tl * 3 + kq - 1) * 1024 + i * 64 + lane] = acc[i];
    }
    __syncthreads();
    if (!kq) {
        const int lr = lane & 31, hi = lane >> 5;
        const int col = col0 + lr;
        const float bv = bias[col];
        #pragma unroll
        for (int i = 0; i < 16; ++i) {
            float v = acc[i] + bv
                    + red[(tl * 3 + 0) * 1024 + i * 64 + lane]
                    + red[(tl * 3 + 1) * 1024 + i * 64 + lane]
                    + red[(tl * 3 + 2) * 1024 + i * 64 + lane];
            const int row = (i & 3) + 8 * (i >> 2) + 4 * hi;
            union { half_t h; unsigned short u; } cv; cv.h = (half_t)v;
            __hip_atomic_store(&dstG[(R0 + row) * Nout + col], cv.u,
                               __ATOMIC_RELAXED, __HIP_MEMORY_SCOPE_AGENT);
        }
    }
}

// ---------------- main: 256 blocks = 2 nets x 32 rowgroups x 4 col-slices ----
__global__ void __launch_bounds__(512, 2) main_kernel(Params p) {
    __shared__ alignas(16) char smem[41024];
    half_t* XA = (half_t*)smem;                 // [16][32][40] f16 (40960 B)
    float* red = (float*)smem;                  // reduce region (overlaps XA)
    float* bsum = (float*)(smem + 40960);

    const int bid = blockIdx.x, tid = threadIdx.x;
    const int net = bid & 1, g = (bid >> 1) & 31, s = bid >> 6;
    const int R0 = g * 32;
    const int w = tid >> 6, lane = tid & 63;

    // ---- L0: a @ w[net] cols [s*128, s*128+128) ----
    stage_a(p.a, XA, R0, tid);
    __syncthreads();
    {
        const int tl = w >> 1, kh = w & 1;          // 4 tiles x 2 k-halves
        const int tile = s * 4 + tl;
        f32x16 acc = mma_tile<4>(XA, p.wt[net], 8, tile, kh * 4, lane);
        reduce2_store(acc, red, tl, kh, lane, p.bias[net], tile * 32,
                      (unsigned short*)p.g_h1[net], HID, R0, true);
    }
    flag_add(p.c1 + (net * 32 + g) * CTR);

    // ---- L1: h1 @ w[2+net] cols [s*128, +128) ----
    flag_wait(p.c1 + (net * 32 + g) * CTR, 4);
    stage_h(p.g_h1[net], XA, R0, tid);
    __syncthreads();
    {
        const int tl = w >> 1, kh = w & 1;          // k-halves of 16 chunks
        const int tile = s * 4 + tl;
        f32x16 acc = mma_tile<8>(XA, p.wt[2 + net], 16, tile, kh * 8, lane);
        reduce2_store(acc, red, tl, kh, lane, p.bias[2 + net], tile * 32,
                      (unsigned short*)p.g_h2[net], HID, R0, true);
    }
    flag_add(p.c2 + (net * 32 + g) * CTR);

    // ---- L2: h2 @ w[4+net] cols [s*64, +64) -> g_mu / g_lv (f16) ----
    flag_wait(p.c2 + (net * 32 + g) * CTR, 4);
    stage_h(p.g_h2[net], XA, R0, tid);
    __syncthreads();
    {
        const int tl = w >> 2, kq = w & 3;          // 2 tiles x 4 k-quarters
        const int tile = s * 2 + tl;
        f32x16 acc = mma_tile<4>(XA, p.wt[4 + net], 16, tile, kq * 4, lane);
        reduce4_store(acc, red, tl, kq, lane, p.bias[4 + net], tile * 32,
                      net ? p.g_lv : p.g_mu, DIM, R0);
    }
    flag_add(p.c3 + g * CTR);

    if (net == 0) return;

    // ---- loss (net==1): 128 blocks x 8 rows, wave w = one row ----
    if (tid == 0) *bsum = 0.f;
    flag_wait(p.c3 + g * CTR, 8);

    const int i = R0 + s * 8 + w;
    const int d0 = lane * 4;
    const half_t* muP = (const half_t*)p.g_mu;
    const half_t* lvP = (const half_t*)p.g_lv;
    half4v mh = *(const half4v*)&muP[i * DIM + d0];
    half4v lh = *(const half4v*)&lvP[i * DIM + d0];
    float4 ebf = *(const float4*)&p.ebsum[d0];
    float4 eb2f = *(const float4*)&p.eb2sum[d0];
    const float invN = 1.0f / (float)N_ROWS;
    float m4[4] = {(float)mh[0], (float)mh[1], (float)mh[2], (float)mh[3]};
    float l4[4] = {(float)lh[0], (float)lh[1], (float)lh[2], (float)lh[3]};
    float eb[4] = {ebf.x * invN, ebf.y * invN, ebf.z * invN, ebf.w * invN};
    float eb2[4] = {eb2f.x * invN, eb2f.y * invN, eb2f.z * invN, eb2f.w * invN};

    float ss = 0.f;
    #pragma unroll
    for (int t = 0; t < 4; ++t) ss = fmaf(m4[t], m4[t], ss);
    #pragma unroll
    for (int o = 32; o > 0; o >>= 1) ss += __shfl_xor(ss, o, 64);
    const float inv_norm = 1.f / fmaxf(sqrtf(ss), 1e-12f);

    float wacc = 0.f;
    #pragma unroll
    for (int t = 0; t < 4; ++t) {
        float mu = m4[t] * inv_norm;
        float lv = tanhf(l4[t]);
        float iv = expf(-lv);
        float diff2 = fmaf(mu, mu, fmaf(-2.f * mu, eb[t], eb2[t]));
        wacc += fmaf(diff2, iv, lv);
    }
    #pragma unroll
    for (int o = 32; o > 0; o >>= 1) wacc += __shfl_xor(wacc, o, 64);
    if (lane == 0) atomicAdd(bsum, wacc);
    __syncthreads();
    if (tid == 0) {
        atomicAdd(p.acc, *bsum);
        asm volatile("s_waitcnt vmcnt(0)" ::: "memory");
        unsigned prev = __hip_atomic_fetch_add(p.done, 1u, __ATOMIC_RELAXED,
                                               __HIP_MEMORY_SCOPE_AGENT);
        if (prev == 127u) {
            float v = __hip_atomic_load(p.acc, __ATOMIC_RELAXED, __HIP_MEMORY_SCOPE_AGENT);
            p.out[0] = v * (1.0f / (float)N_ROWS);
        }
    }
}

extern "C" void kernel_launch(void* const* d_in, const int* in_sizes, int n_in,
                              void* d_out, int out_size, void* d_ws, size_t ws_size,
                              hipStream_t stream) {
    Params p;
    p.a = (const float*)d_in[0];
    p.b = (const float*)d_in[1];
    p.w[0] = (const float*)d_in[2];  p.bias[0] = (const float*)d_in[3];   // mu L0
    p.w[2] = (const float*)d_in[4];  p.bias[2] = (const float*)d_in[5];   // mu L1
    p.w[4] = (const float*)d_in[6];  p.bias[4] = (const float*)d_in[7];   // mu L2
    p.w[1] = (const float*)d_in[8];  p.bias[1] = (const float*)d_in[9];   // lv L0
    p.w[3] = (const float*)d_in[10]; p.bias[3] = (const float*)d_in[11];  // lv L1
    p.w[5] = (const float*)d_in[12]; p.bias[5] = (const float*)d_in[13];  // lv L2

    float* f = (float*)d_ws;
    p.c1   = (unsigned*)f;                  // 64 x CTR
    p.c2   = (unsigned*)(f + 1024);         // 64 x CTR
    p.c3   = (unsigned*)(f + 2048);         // 32 x CTR
    p.acc  = f + 2560;
    p.done = (unsigned*)(f + 2576);
    p.ebsum  = f + 2816;                    // 256
    p.eb2sum = f + 3072;                    // 256
    p.g_mu = (unsigned short*)(f + 4096);   // 1024*256 u16
    p.g_lv = (unsigned short*)(f + 4096 + 65536 * 2);
    half_t* hb = (half_t*)(f + 4096 + 65536 * 4);
    p.g_h1[0] = hb;  hb += N_ROWS * HID;
    p.g_h1[1] = hb;  hb += N_ROWS * HID;
    p.g_h2[0] = hb;  hb += N_ROWS * HID;
    p.g_h2[1] = hb;  hb += N_ROWS * HID;
    p.wt[0] = hb;  hb += HID * DIM;
    p.wt[1] = hb;  hb += HID * DIM;
    p.wt[2] = hb;  hb += HID * HID;
    p.wt[3] = hb;  hb += HID * HID;
    p.wt[4] = hb;  hb += DIM * HID;
    p.wt[5] = hb;  hb += DIM * HID;
    p.out = (float*)d_out;

    hipMemsetAsync(d_ws, 0, 16384, stream);   // counters + acc + done + stats
    prep_kernel<<<dim3(256, 7), 256, 0, stream>>>(p);
    main_kernel<<<256, 512, 0, stream>>>(p);
}